// Round 3
// baseline (176.623 us; speedup 1.0000x reference)
//
#include <hip/hip_runtime.h>
#include <hip/hip_fp16.h>
#include <cmath>

// SVC_63737314673237 round 6: DS-pipe relief via 64x64 wave tiles.
// R5 post-mortem: MFMA floor ~31us of 105us; DS pipe (12 b128 frag reads +
// 12KB DMA writes per wave-phase vs 116cyc matrix) oversubscribed ~3x ==
// measured MfmaUtil 29%. Fragment bytes/MFMA-cyc scale as (Mw+Nw)/(Mw*Nw):
// 64x32 -> 64x64 wave tiles cuts LDS reads AND DMA writes 1.5x per work.
// Block = 128 n-rows x 128 sv-chunk, 4 waves (2m x 2n), mt=4 x nt=4.
// All verified R5 math preserved: split-f16 3-pass GEMM, kv C-tile ==
// 16x16x16 B-frag PV-MFMA reduction, zero-padded ahp + clamped sv rows.
// LDS 64KB -> 2 blocks/CU; acc 160 regs, frags hand-scoped -> no spill.

#define GAMMA 0.01f
constexpr int N  = 8192;
constexpr int D  = 256;
constexpr int S  = 5000;
constexpr int C  = 10;
constexpr int NV = 500;
constexpr int R  = 9;     // C-1
constexpr int SPAD = 5120; // 10 classes x 512 padded cols

typedef _Float16 f16x8 __attribute__((ext_vector_type(8)));
typedef _Float16 f16x4 __attribute__((ext_vector_type(4)));
typedef float    f32x4 __attribute__((ext_vector_type(4)));

__device__ __forceinline__ void gload16(const void* g, void* l) {
    __builtin_amdgcn_global_load_lds(
        (const __attribute__((address_space(1))) void*)g,
        (__attribute__((address_space(3))) void*)l, 16, 0, 0);
}

// ---------------- fused split + norms: one wave per row ---------------------
__global__ __launch_bounds__(256) void prep_kernel(const float* __restrict__ x,
                                                   const float* __restrict__ sv,
                                                   _Float16* __restrict__ xh,
                                                   _Float16* __restrict__ xl,
                                                   _Float16* __restrict__ sh,
                                                   _Float16* __restrict__ sl,
                                                   float* __restrict__ xn,
                                                   float* __restrict__ svn) {
    int gid  = blockIdx.x * blockDim.x + threadIdx.x;
    int wid  = gid >> 6;
    int lane = gid & 63;
    if (wid >= N + S) return;
    bool isx = wid < N;
    int  r   = isx ? wid : wid - N;
    const float* row = isx ? (x + (size_t)r * D) : (sv + (size_t)r * D);
    float4 v = reinterpret_cast<const float4*>(row)[lane];
    float s = v.x * v.x + v.y * v.y + v.z * v.z + v.w * v.w;
#pragma unroll
    for (int off = 32; off > 0; off >>= 1) s += __shfl_xor(s, off, 64);
    float vv[4] = {v.x, v.y, v.z, v.w};
    f16x4 h, l;
#pragma unroll
    for (int k = 0; k < 4; ++k) {
        _Float16 hi = (_Float16)vv[k];
        h[k] = hi;
        l[k] = (_Float16)((vv[k] - (float)hi) * 4096.0f);
    }
    size_t o = (size_t)r * D + lane * 4;
    *(f16x4*)((isx ? xh : sh) + o) = h;
    *(f16x4*)((isx ? xl : sl) + o) = l;
    if (lane == 0) (isx ? xn : svn)[r] = s;
}

// ---------------- a split + padded svnorm -----------------------------------
__global__ __launch_bounds__(256) void prep_a(const float* __restrict__ a,
                                              const float* __restrict__ svn,
                                              _Float16* __restrict__ ah,
                                              _Float16* __restrict__ al,
                                              float* __restrict__ svnp) {
    int idx = blockIdx.x * 256 + threadIdx.x;
    if (idx >= 16 * SPAD) return;
    int r = idx / SPAD, col = idx - r * SPAD;
    int cls = col >> 9, j = col & 511;
    int s = cls * NV + ((j < NV) ? j : NV - 1);
    float av = (r < R && j < NV) ? a[(size_t)r * S + s] : 0.0f;
    _Float16 h = (_Float16)av;
    ah[idx] = h;
    al[idx] = (_Float16)((av - (float)h) * 4096.0f);
    if (r == 0) svnp[col] = svn[s];
}

// ---------------- swapped split-MFMA GEMM + exp + PV-MFMA reduce ------------
// grid: (64 row tiles of 128, 10 classes). block 256 = 4 waves (wm,wn 2x2).
// wave tile: 64 sv x 64 n = 4x4 mfma tiles (16x16x32). 32 phases =
// 4 sv-chunks x 8 kb; gload_lds DMA double-buffer, 1 barrier/phase.
__global__ __launch_bounds__(256, 2) void svc_gemm(const _Float16* __restrict__ xh,
                                                   const _Float16* __restrict__ xl,
                                                   const _Float16* __restrict__ sh,
                                                   const _Float16* __restrict__ sl,
                                                   const _Float16* __restrict__ ahp,
                                                   const _Float16* __restrict__ alp,
                                                   const float* __restrict__ xnorm,
                                                   const float* __restrict__ svnp,
                                                   float* __restrict__ T) {
    __shared__ _Float16 SVs[2][2][128 * 32];  // 32KB: M-operand (sv rows)
    __shared__ _Float16 Xs[2][2][128 * 32];   // 32KB: N-operand (x rows)

    const int tid  = threadIdx.x;
    const int n0   = blockIdx.x * 128;
    const int cls  = blockIdx.y;
    const int w    = tid >> 6;
    const int lane = tid & 63;
    const int wm   = w >> 1;   // splits 128 m
    const int wn   = w & 1;    // splits 128 n
    const int lx   = lane & 15;
    const int quad = lane >> 4;

    // x-norms: n = wn*64 + nt*16 + lx
    float xnr[4];
#pragma unroll
    for (int nt = 0; nt < 4; ++nt)
        xnr[nt] = xnorm[n0 + wn * 64 + nt * 16 + lx];

    // fragment read offsets (f16 units), inverse of staged K-slot perm
    int svoff[4], xoff[4];
#pragma unroll
    for (int mt = 0; mt < 4; ++mt) {
        int row = wm * 64 + mt * 16 + lx;
        svoff[mt] = row * 32 + ((quad - row) & 3) * 8;
    }
#pragma unroll
    for (int nt = 0; nt < 4; ++nt) {
        int row = wn * 64 + nt * 16 + lx;
        xoff[nt] = row * 32 + ((quad - row) & 3) * 8;
    }

    // staging: linear LDS dest (wave-uniform base + lane*16B), swizzle on
    // the global K-offset. Each wave covers rows w*16..w*16+15 (+64 chunk).
    const int arow = tid >> 2, ag = tid & 3;
    const int sg   = (ag + arow) & 3;          // (ag+arow+64)&3 == sg
    const int segend = cls * NV + NV - 1;
    const int ldsw = w * 512;

    auto stage = [&](int ph, int buf) {
        const int ch = ph >> 3, kb = ph & 7;
        const size_t koff = (size_t)(kb * 32 + sg * 8);
        const size_t goX0 = (size_t)(n0 + arow) * D + koff;
        const size_t goX1 = (size_t)(n0 + arow + 64) * D + koff;
        gload16(xh + goX0, &Xs[buf][0][ldsw]);
        gload16(xl + goX0, &Xs[buf][1][ldsw]);
        gload16(xh + goX1, &Xs[buf][0][2048 + ldsw]);
        gload16(xl + goX1, &Xs[buf][1][2048 + ldsw]);
        const int svbase = cls * NV + ch * 128;
        int svr0 = svbase + arow;      if (svr0 > segend) svr0 = segend;
        int svr1 = svbase + arow + 64; if (svr1 > segend) svr1 = segend;
        const size_t go0 = (size_t)svr0 * D + koff;
        const size_t go1 = (size_t)svr1 * D + koff;
        gload16(sh + go0, &SVs[buf][0][ldsw]);
        gload16(sl + go0, &SVs[buf][1][ldsw]);
        gload16(sh + go1, &SVs[buf][0][2048 + ldsw]);
        gload16(sl + go1, &SVs[buf][1][2048 + ldsw]);
    };

    f32x4 accM[4][4], accC[4][4];      // first-GEMM tiles [mt][nt]
#pragma unroll
    for (int mt = 0; mt < 4; ++mt)
#pragma unroll
        for (int nt = 0; nt < 4; ++nt) {
            accM[mt][nt] = (f32x4){0.f, 0.f, 0.f, 0.f};
            accC[mt][nt] = (f32x4){0.f, 0.f, 0.f, 0.f};
        }
    f32x4 accO[4], accOC[4];           // PV output tiles [nt] (r x n)
#pragma unroll
    for (int nt = 0; nt < 4; ++nt) {
        accO[nt]  = (f32x4){0.f, 0.f, 0.f, 0.f};
        accOC[nt] = (f32x4){0.f, 0.f, 0.f, 0.f};
    }

    stage(0, 0);
    __syncthreads();

    for (int ph = 0; ph < 32; ++ph) {
        const int buf = ph & 1;
        if (ph < 31) stage(ph + 1, buf ^ 1);   // DMA overlaps MFMAs

        // B-side (x) fragments resident across mt loop; A-side streamed.
        f16x8 Bx0[4], Bx1[4];
#pragma unroll
        for (int nt = 0; nt < 4; ++nt) {
            Bx0[nt] = *(const f16x8*)(&Xs[buf][0][xoff[nt]]);
            Bx1[nt] = *(const f16x8*)(&Xs[buf][1][xoff[nt]]);
        }
#pragma unroll
        for (int mt = 0; mt < 4; ++mt) {
            f16x8 a0 = *(const f16x8*)(&SVs[buf][0][svoff[mt]]);
            f16x8 a1 = *(const f16x8*)(&SVs[buf][1][svoff[mt]]);
#pragma unroll
            for (int nt = 0; nt < 4; ++nt) {
                accM[mt][nt] = __builtin_amdgcn_mfma_f32_16x16x32_f16(
                    a0, Bx0[nt], accM[mt][nt], 0, 0, 0);
                accC[mt][nt] = __builtin_amdgcn_mfma_f32_16x16x32_f16(
                    a0, Bx1[nt], accC[mt][nt], 0, 0, 0);
                accC[mt][nt] = __builtin_amdgcn_mfma_f32_16x16x32_f16(
                    a1, Bx0[nt], accC[mt][nt], 0, 0, 0);
            }
        }

        __syncthreads();   // vmcnt(0): next buf's DMA landed

        if ((ph & 7) == 7) {   // chunk done: exp + PV-MFMA reduce (no DS)
            const int ch = ph >> 3;
            const int mbase = cls * 512 + ch * 128 + wm * 64;
#pragma unroll
            for (int mt = 0; mt < 4; ++mt) {
                const size_t ao = (size_t)lx * SPAD + mbase + mt * 16 + quad * 4;
                f16x4 afh = *(const f16x4*)(ahp + ao);   // A-frag: a[r=lx, k]
                f16x4 afl = *(const f16x4*)(alp + ao);
                float4 sn4 = *(const float4*)(svnp + mbase + mt * 16 + quad * 4);
#pragma unroll
                for (int nt = 0; nt < 4; ++nt) {
                    f16x4 bh, bl;   // B-frag: kv[k = quad*4+reg, col = lx]
#pragma unroll
                    for (int reg = 0; reg < 4; ++reg) {
                        float dot = accM[mt][nt][reg]
                                  + accC[mt][nt][reg] * (1.0f / 4096.0f);
                        float e  = fmaf(2.0f * GAMMA, dot,
                                        -GAMMA * (xnr[nt] + sn4[reg]));
                        float kv = __expf(e);
                        _Float16 h = (_Float16)kv;
                        bh[reg] = h;
                        bl[reg] = (_Float16)((kv - (float)h) * 4096.0f);
                    }
                    accO[nt]  = __builtin_amdgcn_mfma_f32_16x16x16f16(
                        afh, bh, accO[nt], 0, 0, 0);
                    accOC[nt] = __builtin_amdgcn_mfma_f32_16x16x16f16(
                        afh, bl, accOC[nt], 0, 0, 0);
                    accOC[nt] = __builtin_amdgcn_mfma_f32_16x16x16f16(
                        afl, bh, accOC[nt], 0, 0, 0);
                    accM[mt][nt] = (f32x4){0.f, 0.f, 0.f, 0.f};
                    accC[mt][nt] = (f32x4){0.f, 0.f, 0.f, 0.f};
                }
            }
        }
    }

    // cross-wm reduce via 16KB of reused SVs space, then store T.
    // accO tile: row r = quad*4+reg, col n = wn*64 + nt*16 + lx.
    float* scr = (float*)&SVs[0][0][0];
    if (wm == 0) {
#pragma unroll
        for (int nt = 0; nt < 4; ++nt)
#pragma unroll
            for (int reg = 0; reg < 4; ++reg) {
                int base = ((wn * 4 + nt) * 2) * 256 + (quad * 4 + reg) * 16 + lx;
                scr[base]       = accO[nt][reg];
                scr[base + 256] = accOC[nt][reg];
            }
    }
    __syncthreads();
    if (wm == 1) {
#pragma unroll
        for (int nt = 0; nt < 4; ++nt)
#pragma unroll
            for (int reg = 0; reg < 4; ++reg) {
                int r = quad * 4 + reg;
                if (r < R) {
                    int base = ((wn * 4 + nt) * 2) * 256 + r * 16 + lx;
                    float o  = accO[nt][reg]  + scr[base];
                    float oc = accOC[nt][reg] + scr[base + 256];
                    int n = n0 + wn * 64 + nt * 16 + lx;
                    T[(size_t)n * 90 + r * 10 + cls] = o + oc * (1.0f / 4096.0f);
                }
            }
    }
}

// ---------------- pairwise voting + argmax ----------------------------------
__global__ __launch_bounds__(256) void vote_kernel(const float* __restrict__ T,
                                                   const float* __restrict__ b,
                                                   int* __restrict__ out) {
    int n = blockIdx.x * blockDim.x + threadIdx.x;
    if (n >= N) return;
    const float* Tn = T + (size_t)n * 90;
    float tv[90];
#pragma unroll
    for (int i = 0; i < 90; ++i) tv[i] = Tn[i];
    int counts[C];
#pragma unroll
    for (int k = 0; k < C; ++k) counts[k] = 0;
    int p = 0;
#pragma unroll
    for (int i = 0; i < C; ++i) {
#pragma unroll
        for (int j = i + 1; j < C; ++j) {
            float c = tv[i * 10 + j] + tv[(j - 1) * 10 + i] + b[p];
            if (c > 0.f) counts[i]++; else counts[j]++;
            ++p;
        }
    }
    int best = 0;
#pragma unroll
    for (int k = 1; k < C; ++k)
        if (counts[k] > counts[best]) best = k;
    out[n]     = best;
    out[N + n] = best;
}

extern "C" void kernel_launch(void* const* d_in, const int* in_sizes, int n_in,
                              void* d_out, int out_size, void* d_ws, size_t ws_size,
                              hipStream_t stream) {
    const float* x  = (const float*)d_in[0];   // [8192,256]
    const float* sv = (const float*)d_in[1];   // [5000,256]
    const float* a  = (const float*)d_in[2];   // [9,5000]
    const float* b  = (const float*)d_in[3];   // [45]
    int* out = (int*)d_out;

    char* wp = (char*)d_ws;
    _Float16* xh = (_Float16*)wp;  wp += (size_t)N * D * 2;
    _Float16* xl = (_Float16*)wp;  wp += (size_t)N * D * 2;
    _Float16* sh = (_Float16*)wp;  wp += (size_t)S * D * 2;
    _Float16* sl = (_Float16*)wp;  wp += (size_t)S * D * 2;
    float* xnorm  = (float*)wp;    wp += (size_t)N * 4;
    float* svnorm = (float*)wp;    wp += (size_t)S * 4;
    _Float16* ahp = (_Float16*)wp; wp += (size_t)16 * SPAD * 2;
    _Float16* alp = (_Float16*)wp; wp += (size_t)16 * SPAD * 2;
    float* svnp   = (float*)wp;    wp += (size_t)SPAD * 4;
    float* T      = (float*)wp;

    {   // fused split + norms: one wave per row
        int waves = N + S;
        prep_kernel<<<(waves * 64 + 255) / 256, 256, 0, stream>>>(
            x, sv, xh, xl, sh, sl, xnorm, svnorm);
    }
    {   // a split + padded svnorm
        prep_a<<<(16 * SPAD + 255) / 256, 256, 0, stream>>>(
            a, svnorm, ahp, alp, svnp);
    }
    {   // swapped GEMM + PV-MFMA reduce
        dim3 grid(N / 128, C);
        svc_gemm<<<grid, 256, 0, stream>>>(xh, xl, sh, sl, ahp, alp,
                                           xnorm, svnp, T);
    }
    {   // voting
        vote_kernel<<<N / 256, 256, 0, stream>>>(T, b, out);
    }
}